// Round 5
// baseline (638.536 us; speedup 1.0000x reference)
//
#include <hip/hip_runtime.h>
#include <hip/hip_bf16.h>
#include <stdint.h>

typedef unsigned long long u64;
typedef __hip_bfloat16 bf16;

#define B_   16
#define C_   256
#define N_   1024
#define HID_ 512

// Runtime-dtype input load: bf==1 -> bf16, bf==0 -> fp32.
__device__ __forceinline__ float ldIn(const void* p, long long i, int bf) {
    return bf ? __bfloat162float(((const bf16*)p)[i]) : ((const float*)p)[i];
}

__device__ __forceinline__ u64 shfl_xor_u64(u64 v, int m) {
    unsigned lo = (unsigned)v, hi = (unsigned)(v >> 32);
    lo = __shfl_xor(lo, m, 64);
    hi = __shfl_xor(hi, m, 64);
    return ((u64)hi << 32) | lo;
}

// ---------------------------------------------------------------------------
// Probe input dtype (from x) + fold BN params into per-channel scale/bias.
// ---------------------------------------------------------------------------
__global__ void prep_kernel(const void* xp,
    const void* fc1_b, const void* bn1_g, const void* bn1_b, const void* bn1_m, const void* bn1_v,
    const void* gc_b,  const void* gbn_g, const void* gbn_b, const void* gbn_m, const void* gbn_v,
    const void* bn2_g, const void* bn2_b, const void* bn2_m, const void* bn2_v,
    const void* fc2_b, const void* bn3_g, const void* bn3_b, const void* bn3_m, const void* bn3_v,
    int* flags, float* s1, float* t1, float* Sg, float* Tg, float* s3, float* t3)
{
    __shared__ int sf;
    if (threadIdx.x == 0) {
        // bf16 x: u16[2i] are real values, exponent in narrow band (cnt=64).
        // fp32 x: u16[2i] are low mantissa halves, random bits (cnt~20).
        const unsigned short* u = (const unsigned short*)xp;
        int cnt = 0;
        for (int i = 0; i < 64; ++i) {
            int e = (u[2 * i] >> 7) & 0xFF;
            cnt += (e >= 87 && e <= 167);
        }
        int f = (cnt >= 48) ? 1 : 0;
        flags[0] = f;
        sf = f;
    }
    __syncthreads();
    int bf = sf;
    int i = threadIdx.x;
    if (i < 256) {
        float g = ldIn(bn1_g, i, bf), bb = ldIn(bn1_b, i, bf);
        float m = ldIn(bn1_m, i, bf), v  = ldIn(bn1_v, i, bf);
        float s = g / sqrtf(v + 1e-5f);
        s1[i] = s;
        t1[i] = (ldIn(fc1_b, i, bf) - m) * s + bb;

        float g3 = ldIn(bn3_g, i, bf), b3 = ldIn(bn3_b, i, bf);
        float m3 = ldIn(bn3_m, i, bf), v3 = ldIn(bn3_v, i, bf);
        float ss3 = g3 / sqrtf(v3 + 1e-5f);
        s3[i] = ss3;
        t3[i] = (ldIn(fc2_b, i, bf) - m3) * ss3 + b3;
    }
    if (i < 512) {
        float gg = ldIn(gbn_g, i, bf), gb = ldIn(gbn_b, i, bf);
        float gm = ldIn(gbn_m, i, bf), gv = ldIn(gbn_v, i, bf);
        float sg = gg / sqrtf(gv + 1e-5f);
        float g2 = ldIn(bn2_g, i, bf), b2 = ldIn(bn2_b, i, bf);
        float m2 = ldIn(bn2_m, i, bf), v2 = ldIn(bn2_v, i, bf);
        float s2 = g2 / sqrtf(v2 + 1e-5f);
        Sg[i] = sg * s2;
        Tg[i] = ((ldIn(gc_b, i, bf) - gm) * sg + gb - m2) * s2 + b2;
    }
}

// ---------------------------------------------------------------------------
// Tiled fp32 GEMM: Out[b][o][n] = epi( sum_k A[o][k]*B[b][k][n] )
// EPI 0: *s+t -> fp32 (F).  EPI 2: *s+t + resid -> FP32 (final output).
// A: weight (runtime dtype). B dtype: bcode 2=runtime flag, 1=bf16.
// Tile 64x64, 256 threads, 4x4 per thread, k-chunk 16. N fixed = 1024.
// ---------------------------------------------------------------------------
template<int EPI>
__global__ __launch_bounds__(256)
void gemm_epi(const void* __restrict__ Aw, const void* __restrict__ Bx, long long b0elem,
              void* __restrict__ Out, const float* __restrict__ scale, const float* __restrict__ bias,
              const void* __restrict__ resid, long long r0elem, const int* __restrict__ flags,
              int K, long long strideB, long long strideOut, int bcode)
{
    __shared__ float As[16][68];
    __shared__ float Bs[16][68];

    int inf   = flags[0];
    int bflag = (bcode == 2) ? inf : bcode;

    int b  = blockIdx.z;
    int o0 = blockIdx.y * 64, n0 = blockIdx.x * 64;
    int t  = threadIdx.x;
    int tn = t & 15, to = t >> 4;
    long long bbase = b0elem + (long long)b * strideB;

    float acc[4][4] = {};

    for (int k0 = 0; k0 < K; k0 += 16) {
        {   // A tile: 64 o-rows x 16 k
            int l = t * 4;
            int ao = l >> 4, ak = l & 15;
            long long ai = (long long)(o0 + ao) * K + k0 + ak;
            As[ak + 0][ao] = ldIn(Aw, ai + 0, inf);
            As[ak + 1][ao] = ldIn(Aw, ai + 1, inf);
            As[ak + 2][ao] = ldIn(Aw, ai + 2, inf);
            As[ak + 3][ao] = ldIn(Aw, ai + 3, inf);
        }
        {   // B tile: 16 k-rows x 64 n
            int l = t * 4;
            int bk = l >> 6, bn = l & 63;
            long long bi = bbase + (long long)(k0 + bk) * N_ + n0 + bn;
            Bs[bk][bn + 0] = ldIn(Bx, bi + 0, bflag);
            Bs[bk][bn + 1] = ldIn(Bx, bi + 1, bflag);
            Bs[bk][bn + 2] = ldIn(Bx, bi + 2, bflag);
            Bs[bk][bn + 3] = ldIn(Bx, bi + 3, bflag);
        }
        __syncthreads();
        #pragma unroll
        for (int k = 0; k < 16; ++k) {
            float av[4], bv[4];
            #pragma unroll
            for (int i = 0; i < 4; ++i) av[i] = As[k][to * 4 + i];
            #pragma unroll
            for (int j = 0; j < 4; ++j) bv[j] = Bs[k][tn * 4 + j];
            #pragma unroll
            for (int i = 0; i < 4; ++i)
                #pragma unroll
                for (int j = 0; j < 4; ++j) acc[i][j] += av[i] * bv[j];
        }
        __syncthreads();
    }

    #pragma unroll
    for (int i = 0; i < 4; ++i) {
        int o = o0 + to * 4 + i;
        float s = scale[o], tt = bias[o];
        #pragma unroll
        for (int j = 0; j < 4; ++j) {
            int n = n0 + tn * 4 + j;
            float v = acc[i][j] * s + tt;
            long long oi = (long long)b * strideOut + (long long)o * N_ + n;
            if (EPI == 2) {
                v += ldIn(resid, r0elem + oi, inf);
                ((float*)Out)[oi] = v;      // FP32 output (reference dtype)
            } else {
                ((float*)Out)[oi] = v;
            }
        }
    }
}

// ---------------------------------------------------------------------------
// x2[b][n] = sum_c F[b][c][n]^2   (b local to chunk)
// ---------------------------------------------------------------------------
__global__ __launch_bounds__(256)
void compute_x2(const float* __restrict__ F, float* __restrict__ x2)
{
    int n = blockIdx.x * 256 + threadIdx.x;
    int b = blockIdx.y;
    const float* Fb = F + (long long)b * C_ * N_;
    float s = 0.f;
    for (int c = 0; c < C_; ++c) { float v = Fb[c * N_ + n]; s += v * v; }
    x2[b * N_ + n] = s;
}

// ---------------------------------------------------------------------------
// D[b][q][m] = x2[m] - 2 * sum_c F[c][q]*F[c][m]   (b local; the
// row-constant x2[q] can't change the argsort)
// ---------------------------------------------------------------------------
__global__ __launch_bounds__(256)
void gram_dist(const float* __restrict__ F, const float* __restrict__ x2,
               float* __restrict__ D)
{
    __shared__ float As[16][68];
    __shared__ float Bs[16][68];

    int b  = blockIdx.z;
    int q0 = blockIdx.y * 64, m0 = blockIdx.x * 64;
    int t  = threadIdx.x;
    int tn = t & 15, to = t >> 4;
    const float* Fb = F + (long long)b * C_ * N_;

    float acc[4][4] = {};

    for (int k0 = 0; k0 < C_; k0 += 16) {
        int l = t * 4;
        int lk = l >> 6, ln = l & 63;
        const float* ap = Fb + (long long)(k0 + lk) * N_ + q0 + ln;
        As[lk][ln + 0] = ap[0]; As[lk][ln + 1] = ap[1];
        As[lk][ln + 2] = ap[2]; As[lk][ln + 3] = ap[3];
        const float* bp = Fb + (long long)(k0 + lk) * N_ + m0 + ln;
        Bs[lk][ln + 0] = bp[0]; Bs[lk][ln + 1] = bp[1];
        Bs[lk][ln + 2] = bp[2]; Bs[lk][ln + 3] = bp[3];
        __syncthreads();
        #pragma unroll
        for (int k = 0; k < 16; ++k) {
            float av[4], bv[4];
            #pragma unroll
            for (int i = 0; i < 4; ++i) av[i] = As[k][to * 4 + i];
            #pragma unroll
            for (int j = 0; j < 4; ++j) bv[j] = Bs[k][tn * 4 + j];
            #pragma unroll
            for (int i = 0; i < 4; ++i)
                #pragma unroll
                for (int j = 0; j < 4; ++j) acc[i][j] += av[i] * bv[j];
        }
        __syncthreads();
    }

    const float* x2b = x2 + b * N_;
    #pragma unroll
    for (int i = 0; i < 4; ++i) {
        int q = q0 + to * 4 + i;
        float* Dq = D + ((long long)b * N_ + q) * N_;
        #pragma unroll
        for (int j = 0; j < 4; ++j) {
            int m = m0 + tn * 4 + j;
            Dq[m] = x2b[m] - 2.f * acc[i][j];
        }
    }
}

// ---------------------------------------------------------------------------
// Top-9 smallest per row, ties -> lower index (lax.top_k stability).
// One 64-lane wave per row; keys = sortable fp32 bits <<32 | m (unique).
// ---------------------------------------------------------------------------
__global__ __launch_bounds__(256)
void topk9(const float* __restrict__ D, int* __restrict__ idx)
{
    int row  = blockIdx.x * 4 + (threadIdx.x >> 6);   // local row in chunk
    int lane = threadIdx.x & 63;
    const float* d = D + (long long)row * N_;

    u64 l[9];
    #pragma unroll
    for (int i = 0; i < 9; ++i) l[i] = ~0ULL;

    for (int i = 0; i < N_ / 64; ++i) {
        int m = lane + i * 64;
        float dv = d[m];
        unsigned u = __float_as_uint(dv);
        u = (u & 0x80000000u) ? ~u : (u | 0x80000000u);
        u64 key = ((u64)u << 32) | (unsigned)m;
        if (key < l[8]) {
            u64 x = key;
            #pragma unroll
            for (int j = 0; j < 9; ++j) {
                u64 lo = l[j] < x ? l[j] : x;
                u64 hi = l[j] < x ? x : l[j];
                l[j] = lo; x = hi;
            }
        }
    }

    int* out = idx + (long long)row * 9;
    #pragma unroll
    for (int k = 0; k < 9; ++k) {
        u64 h = l[0];
        #pragma unroll
        for (int s = 32; s >= 1; s >>= 1) {
            u64 o = shfl_xor_u64(h, s);
            if (o < h) h = o;
        }
        int m = (int)(h & 0xFFFFFFFFu);
        if (lane == 0) out[k] = m;
        if (l[0] == h) {   // unique keys: exactly one lane pops
            l[0]=l[1]; l[1]=l[2]; l[2]=l[3]; l[3]=l[4];
            l[4]=l[5]; l[5]=l[6]; l[6]=l[7]; l[7]=l[8]; l[8]=~0ULL;
        }
    }
}

// ---------------------------------------------------------------------------
// DM[b][c][n] = max_k F[c][idx[n][k]] - F[c][n]   (b local to chunk)
// ---------------------------------------------------------------------------
__global__ __launch_bounds__(256)
void build_dm(const float* __restrict__ F, const int* __restrict__ idx,
              bf16* __restrict__ DM)
{
    int n = blockIdx.x * 256 + threadIdx.x;
    int c = blockIdx.y, b = blockIdx.z;
    const float* Fc = F + ((long long)b * C_ + c) * N_;
    const int* id = idx + ((long long)b * N_ + n) * 9;
    float f = Fc[n];
    float nm = -3.4e38f;
    #pragma unroll
    for (int k = 0; k < 9; ++k) nm = fmaxf(nm, Fc[id[k]]);
    DM[((long long)b * C_ + c) * N_ + n] = __float2bfloat16(nm - f);
}

// ---------------------------------------------------------------------------
// gc GEMM with interleaved input channels, no materialized M:
//   G[b][o][n] = gelu( Sg[o]*( sum_c W[o][2c]*F[c][n] + W[o][2c+1]*DM[c][n] ) + Tg[o] )
// ---------------------------------------------------------------------------
__global__ __launch_bounds__(256)
void gemm_gc(const void* __restrict__ W, const float* __restrict__ F,
             const bf16* __restrict__ DM, bf16* __restrict__ G,
             const float* __restrict__ Sg, const float* __restrict__ Tg,
             const int* __restrict__ flags)
{
    __shared__ float As[16][68];
    __shared__ float Bs[16][68];

    int inf = flags[0];
    int b  = blockIdx.z;
    int o0 = blockIdx.y * 64, n0 = blockIdx.x * 64;
    int t  = threadIdx.x;
    int tn = t & 15, to = t >> 4;

    float acc[4][4] = {};

    for (int ph = 0; ph < 2; ++ph) {
        for (int k0 = 0; k0 < C_; k0 += 16) {
            {   // A tile: W[o][2k+ph], strided columns
                int l = t * 4;
                int ao = l >> 4, ak = l & 15;
                long long base = (long long)(o0 + ao) * (2 * C_) + ph;
                As[ak + 0][ao] = ldIn(W, base + 2 * (k0 + ak + 0), inf);
                As[ak + 1][ao] = ldIn(W, base + 2 * (k0 + ak + 1), inf);
                As[ak + 2][ao] = ldIn(W, base + 2 * (k0 + ak + 2), inf);
                As[ak + 3][ao] = ldIn(W, base + 2 * (k0 + ak + 3), inf);
            }
            {   // B tile: F (ph 0) or DM (ph 1)
                int l = t * 4;
                int bk = l >> 6, bn = l & 63;
                long long bi = ((long long)b * C_ + k0 + bk) * N_ + n0 + bn;
                if (ph == 0) {
                    Bs[bk][bn + 0] = F[bi + 0]; Bs[bk][bn + 1] = F[bi + 1];
                    Bs[bk][bn + 2] = F[bi + 2]; Bs[bk][bn + 3] = F[bi + 3];
                } else {
                    Bs[bk][bn + 0] = __bfloat162float(DM[bi + 0]);
                    Bs[bk][bn + 1] = __bfloat162float(DM[bi + 1]);
                    Bs[bk][bn + 2] = __bfloat162float(DM[bi + 2]);
                    Bs[bk][bn + 3] = __bfloat162float(DM[bi + 3]);
                }
            }
            __syncthreads();
            #pragma unroll
            for (int k = 0; k < 16; ++k) {
                float av[4], bv[4];
                #pragma unroll
                for (int i = 0; i < 4; ++i) av[i] = As[k][to * 4 + i];
                #pragma unroll
                for (int j = 0; j < 4; ++j) bv[j] = Bs[k][tn * 4 + j];
                #pragma unroll
                for (int i = 0; i < 4; ++i)
                    #pragma unroll
                    for (int j = 0; j < 4; ++j) acc[i][j] += av[i] * bv[j];
            }
            __syncthreads();
        }
    }

    #pragma unroll
    for (int i = 0; i < 4; ++i) {
        int o = o0 + to * 4 + i;
        float s = Sg[o], tt = Tg[o];
        #pragma unroll
        for (int j = 0; j < 4; ++j) {
            int n = n0 + tn * 4 + j;
            float v = acc[i][j] * s + tt;
            v = 0.5f * v * (1.0f + erff(v * 0.70710678118654752f));
            G[((long long)b * HID_ + o) * N_ + n] = __float2bfloat16(v);
        }
    }
}

// ---------------------------------------------------------------------------
extern "C" void kernel_launch(void* const* d_in, const int* in_sizes, int n_in,
                              void* d_out, int out_size, void* d_ws, size_t ws_size,
                              hipStream_t stream)
{
    // Input-order detection via in_sizes. Dict order has x (4194304) first;
    // alphabetical key order would have it last. Remap defensively.
    const void* p[23];
    if (n_in >= 23 && in_sizes[0] != 4194304 && in_sizes[22] == 4194304) {
        // alphabetical: bn1_b,bn1_g,bn1_m,bn1_v,bn2_b,bn2_g,bn2_m,bn2_v,
        // bn3_b,bn3_g,bn3_m,bn3_v,fc1_b,fc1_w,fc2_b,fc2_w,gbn_b,gbn_g,
        // gbn_m,gbn_v,gc_b,gc_w,x  ->  dict slots:
        const int amap[23] = { // dict slot i takes alphabetical index amap[i]
            22, 13, 12, 1, 0, 2, 3,   // x, fc1_w, fc1_b, bn1_g, bn1_b, bn1_m, bn1_v
            21, 20, 17, 16, 18, 19,   // gc_w, gc_b, gbn_g, gbn_b, gbn_m, gbn_v
            5, 4, 6, 7,               // bn2_g, bn2_b, bn2_m, bn2_v
            15, 14, 9, 8, 10, 11 };   // fc2_w, fc2_b, bn3_g, bn3_b, bn3_m, bn3_v
        for (int i = 0; i < 23; ++i) p[i] = d_in[amap[i]];
    } else {
        for (int i = 0; i < 23; ++i) p[i] = d_in[i];
    }

    const void* x     = p[0];
    const void* fc1_w = p[1];
    const void* fc1_b = p[2];
    const void* bn1_g = p[3];
    const void* bn1_b = p[4];
    const void* bn1_m = p[5];
    const void* bn1_v = p[6];
    const void* gc_w  = p[7];
    const void* gc_b  = p[8];
    const void* gbn_g = p[9];
    const void* gbn_b = p[10];
    const void* gbn_m = p[11];
    const void* gbn_v = p[12];
    const void* bn2_g = p[13];
    const void* bn2_b = p[14];
    const void* bn2_m = p[15];
    const void* bn2_v = p[16];
    const void* fc2_w = p[17];
    const void* fc2_b = p[18];
    const void* bn3_g = p[19];
    const void* bn3_b = p[20];
    const void* bn3_m = p[21];
    const void* bn3_v = p[22];

    char* ws = (char*)d_ws;

    // per-batch scratch (bytes)
    const size_t PB_F  = (size_t)C_ * N_ * 4;     // 1 MiB
    const size_t PB_X2 = (size_t)N_ * 4;          // 4 KiB
    const size_t PB_DM = (size_t)C_ * N_ * 2;     // 512 KiB
    const size_t PB_G  = (size_t)HID_ * N_ * 2;   // 1 MiB
    const size_t PB_D  = (size_t)N_ * N_ * 4;     // 4 MiB
    const size_t PB    = PB_F + PB_X2 + PB_DM + PB_G + PB_D;
    const size_t FIXED = 16384 + (size_t)B_ * N_ * 9 * 4;  // flags+SB+idx

    int CB = 16;
    while (CB > 1 && FIXED + (size_t)CB * PB > ws_size) CB >>= 1;

    int*   flags = (int*)ws;
    float* s1 = (float*)(ws + 256);
    float* t1 = s1 + 256;
    float* s3 = t1 + 256;
    float* t3 = s3 + 256;
    float* Sg = t3 + 256;
    float* Tg = Sg + 512;
    int*   ixAll = (int*)(ws + 16384);
    char*  dyn = ws + FIXED;
    float* F  = (float*)dyn;
    float* x2 = (float*)(dyn + (size_t)CB * PB_F);
    bf16*  DM = (bf16*) (dyn + (size_t)CB * (PB_F + PB_X2));
    bf16*  G  = (bf16*) (dyn + (size_t)CB * (PB_F + PB_X2 + PB_DM));
    float* D  = (float*)(dyn + (size_t)CB * (PB_F + PB_X2 + PB_DM + PB_G));

    prep_kernel<<<1, 512, 0, stream>>>(x,
        fc1_b, bn1_g, bn1_b, bn1_m, bn1_v,
        gc_b, gbn_g, gbn_b, gbn_m, gbn_v,
        bn2_g, bn2_b, bn2_m, bn2_v,
        fc2_b, bn3_g, bn3_b, bn3_m, bn3_v,
        flags, s1, t1, Sg, Tg, s3, t3);

    for (int cb0 = 0; cb0 < B_; cb0 += CB) {
        long long xoff = (long long)cb0 * C_ * N_;
        int* ix = ixAll + (long long)cb0 * N_ * 9;

        // fc1 + BN1 -> F chunk (fp32)
        gemm_epi<0><<<dim3(16, 4, CB), 256, 0, stream>>>(
            fc1_w, x, xoff, F, s1, t1, nullptr, 0, flags,
            C_, (long long)C_ * N_, (long long)C_ * N_, 2);

        compute_x2<<<dim3(4, CB), 256, 0, stream>>>(F, x2);

        gram_dist<<<dim3(16, 16, CB), 256, 0, stream>>>(F, x2, D);

        topk9<<<dim3(CB * N_ / 4), 256, 0, stream>>>(D, ix);

        build_dm<<<dim3(4, C_, CB), 256, 0, stream>>>(F, ix, DM);

        // gc + gbn + bn2 + gelu -> G chunk (bf16)
        gemm_gc<<<dim3(16, 8, CB), 256, 0, stream>>>(
            gc_w, F, DM, G, Sg, Tg, flags);

        // fc2 + bn3 + residual(x) -> out chunk (FP32)
        gemm_epi<2><<<dim3(16, 4, CB), 256, 0, stream>>>(
            fc2_w, G, 0, (float*)d_out + xoff, s3, t3, x, xoff, flags,
            HID_, (long long)HID_ * N_, (long long)C_ * N_, 1);
    }
}

// Round 6
// 364.939 us; speedup vs baseline: 1.7497x; 1.7497x over previous
//
#include <hip/hip_runtime.h>
#include <hip/hip_bf16.h>
#include <stdint.h>

typedef unsigned long long u64;
typedef __hip_bfloat16 bf16;
typedef short s8v __attribute__((ext_vector_type(8)));
typedef short s4v __attribute__((ext_vector_type(4)));
typedef float f4v __attribute__((ext_vector_type(4)));

#define B_   16
#define C_   256
#define N_   1024
#define HID_ 512

// fp32 -> bf16 (round-to-nearest-even), bit-level (no type headaches)
__device__ __forceinline__ unsigned short f2b(float f) {
    unsigned u = __float_as_uint(f);
    unsigned r = (u + 0x7FFFu + ((u >> 16) & 1u)) >> 16;
    return (unsigned short)r;
}
__device__ __forceinline__ float b2f(unsigned short s) {
    return __uint_as_float(((unsigned)s) << 16);
}
// Runtime-dtype input load: bf==1 -> bf16, bf==0 -> fp32.
__device__ __forceinline__ float ldIn(const void* p, long long i, int bf) {
    return bf ? b2f(((const unsigned short*)p)[i]) : ((const float*)p)[i];
}
__device__ __forceinline__ u64 shfl_xor_u64(u64 v, int m) {
    unsigned lo = (unsigned)v, hi = (unsigned)(v >> 32);
    lo = __shfl_xor(lo, m, 64);
    hi = __shfl_xor(hi, m, 64);
    return ((u64)hi << 32) | lo;
}

// ---------------------------------------------------------------------------
// Probe input dtype + fold BN params into per-channel scale/bias.
// ---------------------------------------------------------------------------
__global__ void prep_kernel(const void* xp,
    const void* fc1_b, const void* bn1_g, const void* bn1_b, const void* bn1_m, const void* bn1_v,
    const void* gc_b,  const void* gbn_g, const void* gbn_b, const void* gbn_m, const void* gbn_v,
    const void* bn2_g, const void* bn2_b, const void* bn2_m, const void* bn2_v,
    const void* fc2_b, const void* bn3_g, const void* bn3_b, const void* bn3_m, const void* bn3_v,
    int* flags, float* s1, float* t1, float* Sg, float* Tg, float* s3, float* t3)
{
    __shared__ int sf;
    if (threadIdx.x == 0) {
        const unsigned short* u = (const unsigned short*)xp;
        int cnt = 0;
        for (int i = 0; i < 64; ++i) {
            int e = (u[2 * i] >> 7) & 0xFF;
            cnt += (e >= 87 && e <= 167);
        }
        int f = (cnt >= 48) ? 1 : 0;
        flags[0] = f;
        sf = f;
    }
    __syncthreads();
    int bf = sf;
    int i = threadIdx.x;
    if (i < 256) {
        float g = ldIn(bn1_g, i, bf), bb = ldIn(bn1_b, i, bf);
        float m = ldIn(bn1_m, i, bf), v  = ldIn(bn1_v, i, bf);
        float s = g / sqrtf(v + 1e-5f);
        s1[i] = s;
        t1[i] = (ldIn(fc1_b, i, bf) - m) * s + bb;

        float g3 = ldIn(bn3_g, i, bf), b3 = ldIn(bn3_b, i, bf);
        float m3 = ldIn(bn3_m, i, bf), v3 = ldIn(bn3_v, i, bf);
        float ss3 = g3 / sqrtf(v3 + 1e-5f);
        s3[i] = ss3;
        t3[i] = (ldIn(fc2_b, i, bf) - m3) * ss3 + b3;
    }
    if (i < 512) {
        float gg = ldIn(gbn_g, i, bf), gb = ldIn(gbn_b, i, bf);
        float gm = ldIn(gbn_m, i, bf), gv = ldIn(gbn_v, i, bf);
        float sg = gg / sqrtf(gv + 1e-5f);
        float g2 = ldIn(bn2_g, i, bf), b2 = ldIn(bn2_b, i, bf);
        float m2 = ldIn(bn2_m, i, bf), v2 = ldIn(bn2_v, i, bf);
        float s2 = g2 / sqrtf(v2 + 1e-5f);
        Sg[i] = sg * s2;
        Tg[i] = ((ldIn(gc_b, i, bf) - gm) * sg + gb - m2) * s2 + b2;
    }
}

// ---------------------------------------------------------------------------
// Cast the three weight matrices to bf16 buffers (MFMA operands).
// total elems = 65536 + 262144 + 131072 = 458752 = 1792 * 256
// ---------------------------------------------------------------------------
__global__ __launch_bounds__(256)
void cast_weights(const void* w1, const void* wg, const void* w2,
                  short* W1b, short* Wgb, short* W2b, const int* flags)
{
    int inf = flags[0];
    int i = blockIdx.x * 256 + threadIdx.x;
    if (i < 65536) {
        W1b[i] = (short)f2b(ldIn(w1, i, inf));
    } else if (i < 65536 + 262144) {
        int j = i - 65536;
        Wgb[j] = (short)f2b(ldIn(wg, j, inf));
    } else {
        int j = i - 327680;
        W2b[j] = (short)f2b(ldIn(w2, j, inf));
    }
}

// ---------------------------------------------------------------------------
// fc1 (VALU): Ft[b][n][c] = s1[c] * sum_k w[c][k]*x[b][k][n] + t1[c]
// 64x64 tile, 4x4/thread. Node-major fp32 output.
// ---------------------------------------------------------------------------
__global__ __launch_bounds__(256)
void fc1_valu(const void* __restrict__ Aw, const void* __restrict__ Bx,
              float* __restrict__ Ft, const float* __restrict__ s1,
              const float* __restrict__ t1, const int* __restrict__ flags)
{
    __shared__ float As[16][68];
    __shared__ float Bs[16][68];

    int inf = flags[0];
    int b  = blockIdx.z;
    int o0 = blockIdx.y * 64, n0 = blockIdx.x * 64;
    int t  = threadIdx.x;
    int tn = t & 15, to = t >> 4;
    long long bbase = (long long)b * C_ * N_;

    float acc[4][4] = {};

    for (int k0 = 0; k0 < C_; k0 += 16) {
        {
            int l = t * 4;
            int ao = l >> 4, ak = l & 15;
            long long ai = (long long)(o0 + ao) * C_ + k0 + ak;
            As[ak + 0][ao] = ldIn(Aw, ai + 0, inf);
            As[ak + 1][ao] = ldIn(Aw, ai + 1, inf);
            As[ak + 2][ao] = ldIn(Aw, ai + 2, inf);
            As[ak + 3][ao] = ldIn(Aw, ai + 3, inf);
        }
        {
            int l = t * 4;
            int bk = l >> 6, bn = l & 63;
            long long bi = bbase + (long long)(k0 + bk) * N_ + n0 + bn;
            Bs[bk][bn + 0] = ldIn(Bx, bi + 0, inf);
            Bs[bk][bn + 1] = ldIn(Bx, bi + 1, inf);
            Bs[bk][bn + 2] = ldIn(Bx, bi + 2, inf);
            Bs[bk][bn + 3] = ldIn(Bx, bi + 3, inf);
        }
        __syncthreads();
        #pragma unroll
        for (int k = 0; k < 16; ++k) {
            float av[4], bv[4];
            #pragma unroll
            for (int i = 0; i < 4; ++i) av[i] = As[k][to * 4 + i];
            #pragma unroll
            for (int j = 0; j < 4; ++j) bv[j] = Bs[k][tn * 4 + j];
            #pragma unroll
            for (int i = 0; i < 4; ++i)
                #pragma unroll
                for (int j = 0; j < 4; ++j) acc[i][j] += av[i] * bv[j];
        }
        __syncthreads();
    }

    #pragma unroll
    for (int i = 0; i < 4; ++i) {
        int o = o0 + to * 4 + i;
        float s = s1[o], tt = t1[o];
        #pragma unroll
        for (int j = 0; j < 4; ++j) {
            int n = n0 + tn * 4 + j;
            Ft[((long long)(b << 10) + n) * C_ + o] = acc[i][j] * s + tt;
        }
    }
}

// ---------------------------------------------------------------------------
// prep_F: Ft fp32 [n][c] -> Fhi/Flo bf16 split + x2[n] = sum_c Ft^2
// grid (N/4, B), block 256 = 4 waves; wave per n, lane covers 4 c.
// ---------------------------------------------------------------------------
__global__ __launch_bounds__(256)
void prep_F(const float* __restrict__ Ft, short* __restrict__ Fhi,
            short* __restrict__ Flo, float* __restrict__ x2)
{
    int t = threadIdx.x;
    int wv = t >> 6, lane = t & 63;
    int n = blockIdx.x * 4 + wv;
    int b = blockIdx.y;
    long long base = ((long long)(b << 10) + n) * C_ + lane * 4;
    f4v f = *(const f4v*)(Ft + base);

    s4v hi, lo;
    #pragma unroll
    for (int r = 0; r < 4; ++r) {
        unsigned short h = f2b(f[r]);
        hi[r] = (short)h;
        lo[r] = (short)f2b(f[r] - b2f(h));
    }
    *(s4v*)(Fhi + base) = hi;
    *(s4v*)(Flo + base) = lo;

    float ss = f[0]*f[0] + f[1]*f[1] + f[2]*f[2] + f[3]*f[3];
    #pragma unroll
    for (int s = 32; s >= 1; s >>= 1) ss += __shfl_xor(ss, s, 64);
    if (lane == 0) x2[(b << 10) + n] = ss;
}

// ---------------------------------------------------------------------------
// MFMA gram (A·A^T) with 4-pass hi/lo split:
//   D[bl][q][m] = x2[m] - 2 * sum_c F[q][c]*F[m][c]
// 128x128 tile / block, 4 waves, each 64x64 (4x4 MFMA frags), BK=32.
// ---------------------------------------------------------------------------
__global__ __launch_bounds__(256)
void mfma_gram(const short* __restrict__ Fhi, const short* __restrict__ Flo,
               const float* __restrict__ x2, float* __restrict__ D, int cb0)
{
    __shared__ short As[128][40];
    __shared__ short Bs[128][40];

    int t = threadIdx.x;
    int bl = blockIdx.z, b = cb0 + bl;
    int m0 = blockIdx.x * 128, q0 = blockIdx.y * 128;
    int wv = t >> 6, ln = t & 15, quad = (t >> 4) & 3;
    int wo = (wv & 1) * 64, wn = (wv >> 1) * 64;

    f4v acc[4][4];
    #pragma unroll
    for (int i = 0; i < 4; ++i)
        #pragma unroll
        for (int j = 0; j < 4; ++j) acc[i][j] = 0.f;

    #pragma unroll
    for (int p = 0; p < 4; ++p) {
        const short* SA = (p & 2) ? Flo : Fhi;
        const short* SB = (p & 1) ? Flo : Fhi;
        const short* Ab = SA + ((long long)(b << 10) + q0) * C_;
        const short* Bb = SB + ((long long)(b << 10) + m0) * C_;
        for (int k0 = 0; k0 < C_; k0 += 32) {
            __syncthreads();
            #pragma unroll
            for (int s = 0; s < 2; ++s) {
                int sid = t + s * 256;
                int row = sid >> 2, seg = sid & 3;
                *(s8v*)&As[row][seg * 8] = *(const s8v*)(Ab + (long long)row * C_ + k0 + seg * 8);
                *(s8v*)&Bs[row][seg * 8] = *(const s8v*)(Bb + (long long)row * C_ + k0 + seg * 8);
            }
            __syncthreads();
            s8v a[4], bf[4];
            #pragma unroll
            for (int i = 0; i < 4; ++i) a[i]  = *(s8v*)&As[wo + i * 16 + ln][quad * 8];
            #pragma unroll
            for (int j = 0; j < 4; ++j) bf[j] = *(s8v*)&Bs[wn + j * 16 + ln][quad * 8];
            #pragma unroll
            for (int i = 0; i < 4; ++i)
                #pragma unroll
                for (int j = 0; j < 4; ++j)
                    acc[i][j] = __builtin_amdgcn_mfma_f32_16x16x32_bf16(a[i], bf[j], acc[i][j], 0, 0, 0);
        }
    }

    const float* x2b = x2 + (b << 10);
    #pragma unroll
    for (int i = 0; i < 4; ++i) {
        int qb = q0 + wo + i * 16 + quad * 4;
        #pragma unroll
        for (int j = 0; j < 4; ++j) {
            int m = m0 + wn + j * 16 + ln;
            float xm = x2b[m];
            f4v v = acc[i][j];
            #pragma unroll
            for (int r = 0; r < 4; ++r)
                D[(((long long)(bl << 10) + qb + r) << 10) + m] = xm - 2.f * v[r];
        }
    }
}

// ---------------------------------------------------------------------------
// Top-9 smallest per row, ties -> lower index. One wave per row.
// ---------------------------------------------------------------------------
__global__ __launch_bounds__(256)
void topk9(const float* __restrict__ D, int* __restrict__ idx)
{
    int row  = blockIdx.x * 4 + (threadIdx.x >> 6);
    int lane = threadIdx.x & 63;
    const float* d = D + (long long)row * N_;

    u64 l[9];
    #pragma unroll
    for (int i = 0; i < 9; ++i) l[i] = ~0ULL;

    for (int i = 0; i < N_ / 64; ++i) {
        int m = lane + i * 64;
        float dv = d[m];
        unsigned u = __float_as_uint(dv);
        u = (u & 0x80000000u) ? ~u : (u | 0x80000000u);
        u64 key = ((u64)u << 32) | (unsigned)m;
        if (key < l[8]) {
            u64 x = key;
            #pragma unroll
            for (int j = 0; j < 9; ++j) {
                u64 lo = l[j] < x ? l[j] : x;
                u64 hi = l[j] < x ? x : l[j];
                l[j] = lo; x = hi;
            }
        }
    }

    int* out = idx + (long long)row * 9;
    #pragma unroll
    for (int k = 0; k < 9; ++k) {
        u64 h = l[0];
        #pragma unroll
        for (int s = 32; s >= 1; s >>= 1) {
            u64 o = shfl_xor_u64(h, s);
            if (o < h) h = o;
        }
        int m = (int)(h & 0xFFFFFFFFu);
        if (lane == 0) out[k] = m;
        if (l[0] == h) {
            l[0]=l[1]; l[1]=l[2]; l[2]=l[3]; l[3]=l[4];
            l[4]=l[5]; l[5]=l[6]; l[6]=l[7]; l[7]=l[8]; l[8]=~0ULL;
        }
    }
}

// ---------------------------------------------------------------------------
// build_Mt: Mt[b][n][2c] = bf16(Ft[n][c]); Mt[b][n][2c+1] = bf16(maxdiff)
// grid (N/4, B), block 256 = 4 waves; wave per n, lane covers 4 c.
// ---------------------------------------------------------------------------
__global__ __launch_bounds__(256)
void build_Mt(const float* __restrict__ Ft, const int* __restrict__ idx,
              short* __restrict__ Mt)
{
    int t = threadIdx.x;
    int wv = t >> 6, lane = t & 63;
    int n = blockIdx.x * 4 + wv;
    int b = blockIdx.y;
    int c0 = lane * 4;
    long long nb = (long long)(b << 10) + n;

    f4v f = *(const f4v*)(Ft + nb * C_ + c0);
    const int* id = idx + nb * 9;
    f4v mx = {-3.4e38f, -3.4e38f, -3.4e38f, -3.4e38f};
    #pragma unroll
    for (int k = 0; k < 9; ++k) {
        f4v g = *(const f4v*)(Ft + ((long long)(b << 10) + id[k]) * C_ + c0);
        mx[0] = fmaxf(mx[0], g[0]); mx[1] = fmaxf(mx[1], g[1]);
        mx[2] = fmaxf(mx[2], g[2]); mx[3] = fmaxf(mx[3], g[3]);
    }
    s8v m8;
    #pragma unroll
    for (int r = 0; r < 4; ++r) {
        m8[2 * r]     = (short)f2b(f[r]);
        m8[2 * r + 1] = (short)f2b(mx[r] - f[r]);
    }
    *(s8v*)(Mt + nb * (2 * C_) + 2 * c0) = m8;
}

// ---------------------------------------------------------------------------
// MFMA GEMM: acc[o][n] = sum_k A[o][k] * Bm[b][n][k]
// EPI 0: gelu(acc*s+t) -> bf16 Gt[b][n][Odim]
// EPI 1: acc*s+t + resid -> fp32 out[b][o][1024]
// ---------------------------------------------------------------------------
template<int EPI>
__global__ __launch_bounds__(256)
void mfma_gemm(const short* __restrict__ A, const short* __restrict__ Bm,
               void* __restrict__ Out, const float* __restrict__ scale,
               const float* __restrict__ bias, const void* __restrict__ resid,
               const int* __restrict__ flags, int K, int Odim)
{
    __shared__ short As[128][40];
    __shared__ short Bs[128][40];

    int t = threadIdx.x, b = blockIdx.z;
    int n0 = blockIdx.x * 128, o0 = blockIdx.y * 128;
    int wv = t >> 6, ln = t & 15, quad = (t >> 4) & 3;
    int wo = (wv & 1) * 64, wn = (wv >> 1) * 64;

    f4v acc[4][4];
    #pragma unroll
    for (int i = 0; i < 4; ++i)
        #pragma unroll
        for (int j = 0; j < 4; ++j) acc[i][j] = 0.f;

    const short* Ab = A + (long long)o0 * K;
    const short* Bb = Bm + ((long long)(b << 10) + n0) * K;

    for (int k0 = 0; k0 < K; k0 += 32) {
        __syncthreads();
        #pragma unroll
        for (int s = 0; s < 2; ++s) {
            int sid = t + s * 256;
            int row = sid >> 2, seg = sid & 3;
            *(s8v*)&As[row][seg * 8] = *(const s8v*)(Ab + (long long)row * K + k0 + seg * 8);
            *(s8v*)&Bs[row][seg * 8] = *(const s8v*)(Bb + (long long)row * K + k0 + seg * 8);
        }
        __syncthreads();
        s8v a[4], bf[4];
        #pragma unroll
        for (int i = 0; i < 4; ++i) a[i]  = *(s8v*)&As[wo + i * 16 + ln][quad * 8];
        #pragma unroll
        for (int j = 0; j < 4; ++j) bf[j] = *(s8v*)&Bs[wn + j * 16 + ln][quad * 8];
        #pragma unroll
        for (int i = 0; i < 4; ++i)
            #pragma unroll
            for (int j = 0; j < 4; ++j)
                acc[i][j] = __builtin_amdgcn_mfma_f32_16x16x32_bf16(a[i], bf[j], acc[i][j], 0, 0, 0);
    }

    int inf = flags[0];
    #pragma unroll
    for (int i = 0; i < 4; ++i) {
        int ob = o0 + wo + i * 16 + quad * 4;
        #pragma unroll
        for (int j = 0; j < 4; ++j) {
            int n = n0 + wn + j * 16 + ln;
            f4v v = acc[i][j];
            if (EPI == 0) {
                s4v g;
                #pragma unroll
                for (int r = 0; r < 4; ++r) {
                    float val = v[r] * scale[ob + r] + bias[ob + r];
                    val = 0.5f * val * (1.0f + erff(val * 0.70710678118654752f));
                    g[r] = (short)f2b(val);
                }
                *(s4v*)((short*)Out + ((long long)(b << 10) + n) * Odim + ob) = g;
            } else {
                #pragma unroll
                for (int r = 0; r < 4; ++r) {
                    int o = ob + r;
                    long long oi = ((long long)b * Odim + o) * N_ + n;
                    ((float*)Out)[oi] = v[r] * scale[o] + bias[o] + ldIn(resid, oi, inf);
                }
            }
        }
    }
}

// ---------------------------------------------------------------------------
extern "C" void kernel_launch(void* const* d_in, const int* in_sizes, int n_in,
                              void* d_out, int out_size, void* d_ws, size_t ws_size,
                              hipStream_t stream)
{
    const void* p[23];
    if (n_in >= 23 && in_sizes[0] != 4194304 && in_sizes[22] == 4194304) {
        const int amap[23] = {
            22, 13, 12, 1, 0, 2, 3,
            21, 20, 17, 16, 18, 19,
            5, 4, 6, 7,
            15, 14, 9, 8, 10, 11 };
        for (int i = 0; i < 23; ++i) p[i] = d_in[amap[i]];
    } else {
        for (int i = 0; i < 23; ++i) p[i] = d_in[i];
    }

    const void* x     = p[0];
    const void* fc1_w = p[1];
    const void* fc1_b = p[2];
    const void* bn1_g = p[3];
    const void* bn1_b = p[4];
    const void* bn1_m = p[5];
    const void* bn1_v = p[6];
    const void* gc_w  = p[7];
    const void* gc_b  = p[8];
    const void* gbn_g = p[9];
    const void* gbn_b = p[10];
    const void* gbn_m = p[11];
    const void* gbn_v = p[12];
    const void* bn2_g = p[13];
    const void* bn2_b = p[14];
    const void* bn2_m = p[15];
    const void* bn2_v = p[16];
    const void* fc2_w = p[17];
    const void* fc2_b = p[18];
    const void* bn3_g = p[19];
    const void* bn3_b = p[20];
    const void* bn3_m = p[21];
    const void* bn3_v = p[22];

    char* ws = (char*)d_ws;

    // fixed layout (bytes)
    size_t off = 0;
    int*   flags = (int*)ws;
    float* s1 = (float*)(ws + 256);
    float* t1 = s1 + 256;
    float* s3 = t1 + 256;
    float* t3 = s3 + 256;
    float* Sg = t3 + 256;
    float* Tg = Sg + 512;
    off = 16384;
    int*   ixAll = (int*)(ws + off);  off += (size_t)B_ * N_ * 9 * 4;      // 576 KiB
    short* W1b = (short*)(ws + off);  off += (size_t)C_ * C_ * 2;          // 128 KiB
    short* Wgb = (short*)(ws + off);  off += (size_t)HID_ * 2 * C_ * 2;    // 512 KiB
    short* W2b = (short*)(ws + off);  off += (size_t)C_ * HID_ * 2;        // 256 KiB
    float* Ft  = (float*)(ws + off);  off += (size_t)B_ * N_ * C_ * 4;     // 16 MiB
    short* Fhi = (short*)(ws + off);  off += (size_t)B_ * N_ * C_ * 2;     // 8 MiB
    short* Flo = (short*)(ws + off);  off += (size_t)B_ * N_ * C_ * 2;     // 8 MiB
    float* x2  = (float*)(ws + off);  off += (size_t)B_ * N_ * 4;          // 64 KiB
    short* Mt  = (short*)(ws + off);  off += (size_t)B_ * N_ * 2 * C_ * 2; // 16 MiB
    short* Gt  = (short*)(ws + off);  off += (size_t)B_ * N_ * HID_ * 2;   // 16 MiB
    float* D   = (float*)(ws + off);                                       // CB2 * 4 MiB

    int CB2 = 16;
    while (CB2 > 1 && off + (size_t)CB2 * N_ * N_ * 4 > ws_size) CB2 >>= 1;

    prep_kernel<<<1, 512, 0, stream>>>(x,
        fc1_b, bn1_g, bn1_b, bn1_m, bn1_v,
        gc_b, gbn_g, gbn_b, gbn_m, gbn_v,
        bn2_g, bn2_b, bn2_m, bn2_v,
        fc2_b, bn3_g, bn3_b, bn3_m, bn3_v,
        flags, s1, t1, Sg, Tg, s3, t3);

    cast_weights<<<1792, 256, 0, stream>>>(fc1_w, gc_w, fc2_w, W1b, Wgb, W2b, flags);

    // fc1 + BN1 -> Ft fp32 [b][n][c]
    fc1_valu<<<dim3(16, 4, B_), 256, 0, stream>>>(fc1_w, x, Ft, s1, t1, flags);

    // split + x2
    prep_F<<<dim3(N_ / 4, B_), 256, 0, stream>>>(Ft, Fhi, Flo, x2);

    // gram (MFMA split) + topk, chunked over batches
    for (int cb0 = 0; cb0 < B_; cb0 += CB2) {
        mfma_gram<<<dim3(8, 8, CB2), 256, 0, stream>>>(Fhi, Flo, x2, D, cb0);
        topk9<<<dim3(CB2 * N_ / 4), 256, 0, stream>>>(D, ixAll + (long long)cb0 * N_ * 9);
    }

    // interleaved gc input [b][n][2c] bf16
    build_Mt<<<dim3(N_ / 4, B_), 256, 0, stream>>>(Ft, ixAll, Mt);

    // gc + gbn + bn2 + gelu -> Gt bf16 [b][n][512]
    mfma_gemm<0><<<dim3(8, 4, B_), 256, 0, stream>>>(
        Wgb, Mt, Gt, Sg, Tg, nullptr, flags, 2 * C_, HID_);

    // fc2 + bn3 + residual(x) -> out fp32 [b][256][1024]
    mfma_gemm<1><<<dim3(8, 2, B_), 256, 0, stream>>>(
        W2b, Gt, d_out, s3, t3, x, flags, HID_, C_);
}